// Round 8
// baseline (487.294 us; speedup 1.0000x reference)
//
#include <hip/hip_runtime.h>

// Dynamic per-group (G=128) asymmetric int8 fake-quantize, fp32 in/out.
// TWO-KERNEL split: K1 (observer) computes per-group {scale, inv, zp, nzs}
// into d_ws; K2 (apply) is a pure elementwise stream with no cross-lane ops,
// no divides, and no dependency join -> freely pipelineable.
// K1 uses plain loads so x fills L3 (256 MiB = L3 size); K2 re-reads x
// (mostly L3 hits) and NT-stores out (bypass caches, keep x resident).

typedef float f32x4 __attribute__((ext_vector_type(4)));

constexpr float QMIN = -128.0f;
constexpr float QMAX = 127.0f;
constexpr float EPSF = 1.1920928955078125e-07f;  // fp32 eps

__device__ __forceinline__ float min4(f32x4 v) {
  return fminf(fminf(v.x, v.y), fminf(v.z, v.w));
}
__device__ __forceinline__ float max4(f32x4 v) {
  return fmaxf(fmaxf(v.x, v.y), fmaxf(v.z, v.w));
}

// K1: per-group min/max observer. 16 consecutive lanes own one group
// (128 floats = 32 float4s); each lane loads float4 #l and #(l+16).
// Butterfly over masks 1,2,4,8 stays within the 16-lane subgroup.
__global__ __launch_bounds__(256) void dsq_obs(
    const float* __restrict__ x, f32x4* __restrict__ params, int n8) {
  const f32x4* __restrict__ x4 = reinterpret_cast<const f32x4*>(x);

  int t = blockIdx.x * blockDim.x + threadIdx.x;
  int nthreads = gridDim.x * blockDim.x;

  for (int p = t; p < n8; p += nthreads) {
    int i0 = ((p >> 4) << 5) + (p & 15);
    f32x4 v0 = x4[i0];
    f32x4 v1 = x4[i0 + 16];

    float mn = fminf(min4(v0), min4(v1));
    float mx = fmaxf(max4(v0), max4(v1));

    #pragma unroll
    for (int m = 1; m < 16; m <<= 1) {
      mn = fminf(mn, __shfl_xor(mn, m, 64));
      mx = fmaxf(mx, __shfl_xor(mx, m, 64));
    }

    if ((p & 15) == 0) {
      mn = fminf(mn, 0.0f);  // observer always includes zero
      mx = fmaxf(mx, 0.0f);
      float scale = fmaxf((mx - mn) * (1.0f / 255.0f), EPSF);
      float inv = 1.0f / scale;
      float zp = fminf(fmaxf(rintf(QMIN - mn / scale), QMIN), QMAX);
      f32x4 pr;
      pr.x = scale; pr.y = inv; pr.z = zp; pr.w = -zp * scale;
      // lanes 0,16,32,48 of a wave write 4x16B contiguous (64B line)
      params[p >> 4] = pr;
    }
  }
}

// K2: elementwise quant-dequant. No reduction, no divide -> pipelineable.
__global__ __launch_bounds__(256) void dsq_apply(
    const float* __restrict__ x, const f32x4* __restrict__ params,
    float* __restrict__ out, int n4) {
  const f32x4* __restrict__ x4 = reinterpret_cast<const f32x4*>(x);
  f32x4* __restrict__ o4 = reinterpret_cast<f32x4*>(out);

  int t = blockIdx.x * blockDim.x + threadIdx.x;
  int nthreads = gridDim.x * blockDim.x;

  #pragma unroll 2
  for (int i = t; i < n4; i += nthreads) {
    f32x4 v = x4[i];
    f32x4 pr = params[i >> 5];  // 32 float4s per group
    float scale = pr.x, inv = pr.y, zp = pr.z, nzs = pr.w;

    f32x4 o;
    o.x = fmaf(fminf(fmaxf(rintf(v.x * inv) + zp, QMIN), QMAX), scale, nzs);
    o.y = fmaf(fminf(fmaxf(rintf(v.y * inv) + zp, QMIN), QMAX), scale, nzs);
    o.z = fmaf(fminf(fmaxf(rintf(v.z * inv) + zp, QMIN), QMAX), scale, nzs);
    o.w = fmaf(fminf(fmaxf(rintf(v.w * inv) + zp, QMIN), QMAX), scale, nzs);

    __builtin_nontemporal_store(o, &o4[i]);
  }
}

extern "C" void kernel_launch(void* const* d_in, const int* in_sizes, int n_in,
                              void* d_out, int out_size, void* d_ws, size_t ws_size,
                              hipStream_t stream) {
  const float* x = (const float*)d_in[0];
  float* out = (float*)d_out;
  f32x4* params = (f32x4*)d_ws;  // 512K groups x 16B = 8 MB scratch

  int n8 = out_size / 8;  // K1 work units (8 floats each)
  int n4 = out_size / 4;  // K2 float4 count

  dsq_obs<<<2048, 256, 0, stream>>>(x, params, n8);
  dsq_apply<<<2048, 256, 0, stream>>>(x, params, out, n4);
}

// Round 9
// 443.513 us; speedup vs baseline: 1.0987x; 1.0987x over previous
//
#include <hip/hip_runtime.h>

// Dynamic per-group (G=128) asymmetric int8 fake-quantize, fp32 in/out.
// FUSED one-pass (split was -55us: extra x re-read not absorbed by L3).
// Mapping (measured best): 16 consecutive lanes own one group; each lane
// loads float4 #l and #(l+16) -> wave accesses = 256B segments.
// NEW: manual depth-1 software pipeline — iteration i+1's loads are issued
// BEFORE iteration i's reduce/shfl/quant chain, so HBM latency hides under
// compute (compiler didn't pipeline on its own: VGPR_Count was 28).
// One IEEE divide per group; zp via fmaf(-mn, inv, QMIN); dequant = 1 FMA.

typedef float f32x4 __attribute__((ext_vector_type(4)));

constexpr float QMIN = -128.0f;
constexpr float QMAX = 127.0f;
constexpr float EPSF = 1.1920928955078125e-07f;  // fp32 eps

__device__ __forceinline__ float min4(f32x4 v) {
  return fminf(fminf(v.x, v.y), fminf(v.z, v.w));
}
__device__ __forceinline__ float max4(f32x4 v) {
  return fmaxf(fmaxf(v.x, v.y), fmaxf(v.z, v.w));
}

__device__ __forceinline__ void process_store(f32x4 v0, f32x4 v1,
                                              f32x4* __restrict__ o4, int i0) {
  float mn = fminf(min4(v0), min4(v1));
  float mx = fmaxf(max4(v0), max4(v1));

  // butterfly across the 16 lanes owning this group
  #pragma unroll
  for (int m = 1; m < 16; m <<= 1) {
    mn = fminf(mn, __shfl_xor(mn, m, 64));
    mx = fmaxf(mx, __shfl_xor(mx, m, 64));
  }

  mn = fminf(mn, 0.0f);  // observer always includes zero
  mx = fmaxf(mx, 0.0f);

  float scale = fmaxf((mx - mn) * (1.0f / 255.0f), EPSF);
  float inv = 1.0f / scale;  // the only divide
  float zp = fminf(fmaxf(rintf(fmaf(-mn, inv, QMIN)), QMIN), QMAX);
  float nzs = -zp * scale;  // dequant: o = fma(q, scale, nzs)

  f32x4 o0, o1;
  #define QDQ(e) fmaf(fminf(fmaxf(rintf((e) * inv) + zp, QMIN), QMAX), scale, nzs)
  o0.x = QDQ(v0.x); o0.y = QDQ(v0.y); o0.z = QDQ(v0.z); o0.w = QDQ(v0.w);
  o1.x = QDQ(v1.x); o1.y = QDQ(v1.y); o1.z = QDQ(v1.z); o1.w = QDQ(v1.w);
  #undef QDQ

  __builtin_nontemporal_store(o0, &o4[i0]);
  __builtin_nontemporal_store(o1, &o4[i0 + 16]);
}

__global__ __launch_bounds__(256) void dsq_kernel(
    const float* __restrict__ x, float* __restrict__ out, int n8) {
  const f32x4* __restrict__ x4 = reinterpret_cast<const f32x4*>(x);
  f32x4* __restrict__ o4 = reinterpret_cast<f32x4*>(out);

  int t = blockIdx.x * blockDim.x + threadIdx.x;
  int nthreads = gridDim.x * blockDim.x;
  if (t >= n8) return;

  // prologue: load iteration 0
  int i0 = ((t >> 4) << 5) + (t & 15);
  f32x4 c0 = x4[i0];
  f32x4 c1 = x4[i0 + 16];

  for (int p = t + nthreads; p < n8; p += nthreads) {
    int i1 = ((p >> 4) << 5) + (p & 15);
    // prefetch next iteration BEFORE processing current
    f32x4 nx0 = x4[i1];
    f32x4 nx1 = x4[i1 + 16];
    process_store(c0, c1, o4, i0);
    c0 = nx0; c1 = nx1; i0 = i1;
  }
  // epilogue
  process_store(c0, c1, o4, i0);
}

extern "C" void kernel_launch(void* const* d_in, const int* in_sizes, int n_in,
                              void* d_out, int out_size, void* d_ws, size_t ws_size,
                              hipStream_t stream) {
  const float* x = (const float*)d_in[0];
  float* out = (float*)d_out;
  int n8 = out_size / 8;  // 8 floats per thread-iteration; 16 iters/thread

  // 2048 blocks x 256 thr = 524288 threads = exactly full residency
  dsq_kernel<<<2048, 256, 0, stream>>>(x, out, n8);
}